// Round 4
// baseline (7901.945 us; speedup 1.0000x reference)
//
#include <hip/hip_runtime.h>
#include <stdint.h>

// Problem constants (B=4, N=4096, D=512, K=16384, NUM_Q=2)
constexpr int TT = 16384;   // tokens = B*N
constexpr int DD = 512;     // feature dim
constexpr int KK = 16384;   // codebook size
constexpr int TOPK = 8;     // exact-rescore candidates per token

typedef __bf16 bf16x8 __attribute__((ext_vector_type(8)));
typedef __bf16 bf16x4 __attribute__((ext_vector_type(4)));
typedef float f32x4 __attribute__((ext_vector_type(4)));

typedef const __attribute__((address_space(1))) void* gas_ptr;
typedef __attribute__((address_space(3))) void* las_ptr;

// Monotone float -> sortable u32, packed with index. u64 min == (min dist, then min idx),
// matching np.argmin first-occurrence tie-break. (used in exact rescore)
__device__ __forceinline__ unsigned long long pack_di(float d, int idx) {
    uint32_t u = __float_as_uint(d);
    u = (u & 0x80000000u) ? ~u : (u | 0x80000000u);
    return ((unsigned long long)u << 32) | (uint32_t)idx;
}

__device__ __forceinline__ unsigned long long umin64(unsigned long long a,
                                                     unsigned long long b) {
    return a < b ? a : b;
}
__device__ __forceinline__ uint32_t umin32(uint32_t a, uint32_t b) { return a < b ? a : b; }
__device__ __forceinline__ uint32_t umax32(uint32_t a, uint32_t b) { return a > b ? a : b; }

// fp32 -> sortable u32 (monotone)
__device__ __forceinline__ uint32_t sortable(float d) {
    uint32_t u = __float_as_uint(d);
    return u ^ ((uint32_t)((int32_t)u >> 31) | 0x80000000u);
}

// ---------------------------------------------------------------------------
// bf16-MFMA GEMM with fp32-grade accuracy via hi/lo split (3 products):
//   out[m][n] = sum_k Ain[m][k] * W[n][k] + bias[n]
// MODE 0: Ain = A       ; writes out0 (z), out1 (r copy), out2 (bf16 z)
// MODE 1: Ain = A - A2  ; writes out0 only
// 128x128 tile, BK=64, 4 waves 4x1 (32 rows x 128 cols each). N = 512.
// ---------------------------------------------------------------------------
template<int MODE>
__global__ __launch_bounds__(256)
void gemm_mfma(const float* __restrict__ A, const float* __restrict__ A2,
               const float* __restrict__ W, const float* __restrict__ bias,
               float* __restrict__ out0, float* __restrict__ out1,
               __bf16* __restrict__ out2)
{
    __shared__ __bf16 Ah[128 * 64], Al[128 * 64];
    __shared__ __bf16 Bh[128 * 64], Bl[128 * 64];   // 64 KB total
    const int tid = threadIdx.x;
    const int lane = tid & 63;
    const int w = tid >> 6;
    const int row0 = blockIdx.y * 128;
    const int col0 = blockIdx.x * 128;

    f32x4 acc[2][8] = {};

    // staging coords: thread t covers (row = i*16 + t>>4, fp32 cols scol..scol+3)
    const int sr = tid >> 4;            // 0..15
    const int scol = (tid & 15) * 4;    // 0..60
    const int lcol = (((scol >> 3) ^ (sr & 7)) << 3) + (scol & 7);

    int a_off[2], b_off[8];
    #pragma unroll
    for (int mi = 0; mi < 2; ++mi) {
        const int ar = w * 32 + mi * 16 + (lane & 15);
        a_off[mi] = ar * 64 + (((lane >> 4) ^ (ar & 7)) << 3);
    }
    #pragma unroll
    for (int ni = 0; ni < 8; ++ni) {
        const int br = ni * 16 + (lane & 15);
        b_off[ni] = br * 64 + (((lane >> 4) ^ (br & 7)) << 3);
    }

    for (int kb = 0; kb < 512; kb += 64) {
        __syncthreads();
        #pragma unroll
        for (int i = 0; i < 8; ++i) {
            const int r = i * 16 + sr;
            float4 v = *(const float4*)(A + (size_t)(row0 + r) * 512 + kb + scol);
            if (MODE == 1) {
                const float4 u = *(const float4*)(A2 + (size_t)(row0 + r) * 512 + kb + scol);
                v.x -= u.x; v.y -= u.y; v.z -= u.z; v.w -= u.w;
            }
            bf16x4 hv, lv;
            hv[0] = (__bf16)v.x; hv[1] = (__bf16)v.y; hv[2] = (__bf16)v.z; hv[3] = (__bf16)v.w;
            lv[0] = (__bf16)(v.x - (float)hv[0]); lv[1] = (__bf16)(v.y - (float)hv[1]);
            lv[2] = (__bf16)(v.z - (float)hv[2]); lv[3] = (__bf16)(v.w - (float)hv[3]);
            *(bf16x4*)(Ah + r * 64 + lcol) = hv;
            *(bf16x4*)(Al + r * 64 + lcol) = lv;

            const float4 x = *(const float4*)(W + (size_t)(col0 + r) * 512 + kb + scol);
            bf16x4 hw, lw;
            hw[0] = (__bf16)x.x; hw[1] = (__bf16)x.y; hw[2] = (__bf16)x.z; hw[3] = (__bf16)x.w;
            lw[0] = (__bf16)(x.x - (float)hw[0]); lw[1] = (__bf16)(x.y - (float)hw[1]);
            lw[2] = (__bf16)(x.z - (float)hw[2]); lw[3] = (__bf16)(x.w - (float)hw[3]);
            *(bf16x4*)(Bh + r * 64 + lcol) = hw;
            *(bf16x4*)(Bl + r * 64 + lcol) = lw;
        }
        __syncthreads();
        #pragma unroll
        for (int s = 0; s < 2; ++s) {
            const int sx = s * 32;
            bf16x8 ah[2], al[2];
            #pragma unroll
            for (int mi = 0; mi < 2; ++mi) {
                ah[mi] = *(const bf16x8*)(Ah + (a_off[mi] ^ sx));
                al[mi] = *(const bf16x8*)(Al + (a_off[mi] ^ sx));
            }
            #pragma unroll
            for (int ni = 0; ni < 8; ++ni) {
                const bf16x8 bh = *(const bf16x8*)(Bh + (b_off[ni] ^ sx));
                const bf16x8 bl = *(const bf16x8*)(Bl + (b_off[ni] ^ sx));
                #pragma unroll
                for (int mi = 0; mi < 2; ++mi) {
                    acc[mi][ni] = __builtin_amdgcn_mfma_f32_16x16x32_bf16(ah[mi], bh, acc[mi][ni], 0, 0, 0);
                    acc[mi][ni] = __builtin_amdgcn_mfma_f32_16x16x32_bf16(ah[mi], bl, acc[mi][ni], 0, 0, 0);
                    acc[mi][ni] = __builtin_amdgcn_mfma_f32_16x16x32_bf16(al[mi], bh, acc[mi][ni], 0, 0, 0);
                }
            }
        }
    }

    #pragma unroll
    for (int mi = 0; mi < 2; ++mi) {
        #pragma unroll
        for (int reg = 0; reg < 4; ++reg) {
            const int row = row0 + w * 32 + mi * 16 + (lane >> 4) * 4 + reg;
            #pragma unroll
            for (int ni = 0; ni < 8; ++ni) {
                const int col = col0 + ni * 16 + (lane & 15);
                const float o = acc[mi][ni][reg] + bias[col];
                out0[(size_t)row * 512 + col] = o;
                if (MODE == 0) {
                    out1[(size_t)row * 512 + col] = o;
                    out2[(size_t)row * 512 + col] = (__bf16)o;
                }
            }
        }
    }
}

// ---------------------------------------------------------------------------
// Approx distance pass, 256x256 tile, BK=32 dbuf, 64 KB LDS -> 2 BLOCKS/CU:
//   d[t][c] ~= csq[c] - 2 * (r16[t] . cb16[c])
// R3 post-mortem: all schedule variants pinned at ~33% MfmaUtil with BOTH
// pipes idle ~66% -- every stall class (barrier skew, lgkm/vmcnt drains) is
// per-block and at 128 KB LDS only ONE block fits per CU, so nothing fills
// the bubbles. This version halves LDS (BK 64->32, dbuf = 64 KB) so TWO
// independent blocks co-reside (4 waves/SIMD); cross-block wave-level
// overlap (m114) fills each block's sync gaps. MFMA demand per SIMD becomes
// ~1.9x the per-step wall -> MFMA pipe becomes the limiter.
// Per K-step (32 k): read 12 frags | lgkm0 | BAR1 | stage step s+2 (same
// buffer, now safe) | 32 MFMA | vmcnt(4) | BAR2. Ledger: at vmcnt(4),
// outstanding = stage(s+1)[4] + stage(s+2)[4]; retiring to 4 completes
// exactly stage(s+1) = next step's buffer. Tail steps drain to 0.
// BK=32 swizzle: physical 16B chunk = logical ^ ((row>>1)&3) (row stride
// 64 B = half a bank span; (parity,chunk) pairs tile all 32 banks, worst
// aliasing 2-way = free). Grid 512 = ALL blocks resident in one round.
// XCD column-stripe + CHAIN=8 token tiles per block kept from R2/R3.
// Epilogue per finished token tile: top-2 over wave's 64 cols, u32 keys,
// identical layout/tie-break as before.
// ---------------------------------------------------------------------------
constexpr int CHAIN = 8;                      // token tiles chained per block
constexpr int NSTEP = 16 * CHAIN;             // K-steps of 32 per block
constexpr size_t TILE_A = 256 * 512;          // elems per token tile

__global__ __launch_bounds__(512, 4)
void dist_approx8(const __bf16* __restrict__ Rh,   // [TT][512]
                  const __bf16* __restrict__ Ch,   // [KK][512]
                  const float* __restrict__ csq,
                  uint32_t* __restrict__ winners)
{
    __shared__ __bf16 As[2][256 * 32];   // 32 KB
    __shared__ __bf16 Bs[2][256 * 32];   // 32 KB  -> 64 KB total, 2 blocks/CU

    const int tid  = threadIdx.x;
    const int lane = tid & 63;
    const int w    = tid >> 6;        // 0..7
    const int wm   = w >> 2;          // 0..1 : token half (128 rows)
    const int wn   = w & 3;           // 0..3 : code quarter (64 cols)

    // XCD column-stripe: xcd = b&7 owns code-cols [8*xcd, 8*xcd+8)
    const int b    = blockIdx.x;              // 0..511
    const int xcd  = b & 7;
    const int i    = b >> 3;                  // 0..63
    const int ct   = xcd * 8 + (i & 7);       // code tile 0..63
    const int tg   = i >> 3;                  // token group 0..7
    const int col0 = ct << 8;                 // code tile base
    const int rowb = tg << 11;                // 2048-token group base

    f32x4 acc[8][4] = {};   // [mi][ni]

    // staging coords: LDS stays linear for global_load_lds; swizzle applied on
    // the GLOBAL side. Row = tid>>2 (0..127; +128 in 2nd load), 16B chunk
    // (tid&3) holds logical chunk (tid&3)^((row>>1)&3)  (involution).
    const int s_r = tid >> 2;                          // 0..127
    const int s_c = (tid & 3) ^ ((s_r >> 1) & 3);      // logical 16B chunk
    const __bf16* aS = Rh + (size_t)(rowb + s_r) * 512 + s_c * 8;
    const __bf16* bS = Ch + (size_t)(col0 + s_r) * 512 + s_c * 8;
    // 2nd load covers rows +128; its swizzle term: ((s_r+128)>>1)&3 ==
    // (s_r>>1)&3  (128>>1 = 64, 64&3 = 0)  -> same s_c works for both.
    __bf16* const lA0 = &As[0][0]; __bf16* const lA1 = &As[1][0];
    __bf16* const lB0 = &Bs[0][0]; __bf16* const lB1 = &Bs[1][0];

    // A-source offset for K-step q (q = 0..NSTEP-1): tile (q>>4), k-block (q&15)
#define AOFF(q) ((size_t)((q) >> 4) * TILE_A + (size_t)((q) & 15) * 32)
#define BOFF(q) ((size_t)((q) & 15) * 32)

    // one K-step panel (256 rows x 32 cols) = 2 x (512 thr x 16 B) = 16 KB
    // wave-uniform LDS bases: wave w -> rows [16w,16w+16) and [128+16w, ...)
#define STAGE(SRC, UOFF, DST)                                                      \
    {                                                                              \
        __builtin_amdgcn_global_load_lds((gas_ptr)((SRC) + (UOFF)),                \
                                         (las_ptr)((DST) + w * 512), 16, 0, 0);    \
        __builtin_amdgcn_global_load_lds((gas_ptr)((SRC) + (UOFF) + 128 * 512),    \
                                         (las_ptr)((DST) + 128 * 32 + w * 512), 16, 0, 0); \
    }

    // fragment LDS offsets (elems), swizzle-compensated
    int aoff[8], boff[4];
    #pragma unroll
    for (int mi = 0; mi < 8; ++mi) {
        const int r = wm * 128 + mi * 16 + (lane & 15);
        aoff[mi] = r * 32 + ((((lane >> 4) ^ ((r >> 1) & 3))) << 3);
    }
    #pragma unroll
    for (int ni = 0; ni < 4; ++ni) {
        const int r = wn * 64 + ni * 16 + (lane & 15);
        boff[ni] = r * 32 + ((((lane >> 4) ^ ((r >> 1) & 3))) << 3);
    }

#define BAR __builtin_amdgcn_s_barrier()
// full lgkm drain + scheduling fence: this wave's ds_reads have COMPLETED
// (data in VGPRs) before anything below (barrier / MFMA) runs.
#define LGKM0 { asm volatile("s_waitcnt lgkmcnt(0)" ::: "memory"); \
                __builtin_amdgcn_sched_barrier(0); }
#define MFMA32(AF, BV)                                                         \
    {                                                                          \
        __builtin_amdgcn_s_setprio(1);                                         \
        _Pragma("unroll")                                                      \
        for (int mi = 0; mi < 8; ++mi) {                                       \
            _Pragma("unroll")                                                  \
            for (int ni = 0; ni < 4; ++ni)                                     \
                acc[mi][ni] = __builtin_amdgcn_mfma_f32_16x16x32_bf16(         \
                    (AF)[mi], (BV)[ni], acc[mi][ni], 0, 0, 0);                 \
        }                                                                      \
        __builtin_amdgcn_s_setprio(0);                                         \
    }

// one K-step: read frags from (LA,LB); drain; BAR1 licenses same-buffer
// overwrite; stage step S+2; 32 MFMA; counted vmcnt retires stage(S+1);
// BAR2 licenses next step's buffer reads.
#define STEP(LA, LB, S)                                                        \
    {                                                                          \
        _Pragma("unroll")                                                      \
        for (int mi = 0; mi < 8; ++mi) af[mi] = *(const bf16x8*)((LA) + aoff[mi]); \
        _Pragma("unroll")                                                      \
        for (int ni = 0; ni < 4; ++ni) bfr[ni] = *(const bf16x8*)((LB) + boff[ni]); \
        LGKM0;                                                                 \
        BAR;                                                                   \
        const bool more_ = (S) + 2 < NSTEP;                                    \
        if (more_) {                                                           \
            STAGE(aS, AOFF((S) + 2), (LA));                                    \
            STAGE(bS, BOFF((S) + 2), (LB));                                    \
        }                                                                      \
        MFMA32(af, bfr);                                                       \
        if (more_) { asm volatile("s_waitcnt vmcnt(4)" ::: "memory"); }        \
        else       { asm volatile("s_waitcnt vmcnt(0)" ::: "memory"); }        \
        BAR;                                                                   \
    }

    // ---- csq hoist (col0 is block-invariant); oldest vm ops, retired by the
    // prologue vmcnt(4) regardless of compiler ordering (ledger stays safe
    // either way since vmcnt retires in issue order).
    float csv[4];
    #pragma unroll
    for (int ni = 0; ni < 4; ++ni)
        csv[ni] = csq[col0 + wn * 64 + ni * 16 + (lane & 15)];
    const int gt = (col0 >> 6) + wn;   // winners 64-col granule index

    // ---- prologue: step0 A+B -> buf0 (4 loads), step1 A+B -> buf1 (4 loads)
    STAGE(aS, AOFF(0), lA0);
    STAGE(bS, BOFF(0), lB0);
    STAGE(aS, AOFF(1), lA1);
    STAGE(bS, BOFF(1), lB1);
    asm volatile("s_waitcnt vmcnt(4)" ::: "memory");
    BAR;

    bf16x8 af[8], bfr[4];

    for (int it = 0; it < 8 * CHAIN; ++it) {
        STEP(lA0, lB0, 2 * it);          // even step: buffer 0
        STEP(lA1, lB1, 2 * it + 1);      // odd step:  buffer 1

        // ---- per-tile epilogue: token tile finished every 8 iterations.
        // Top-2 over this wave's 64 cols, u32 keys; C/D layout (16x16x32):
        // col = lane&15, row = (lane>>4)*4 + reg.  Then re-zero acc.
        // Winner stores enter the vmcnt queue; the next step's vmcnt(4) is
        // then conservative (waits longer), never unsafe.
        if ((it & 7) == 7) {
            const int r0t = rowb + (it >> 3) * 256;
            #pragma unroll
            for (int mi = 0; mi < 8; ++mi) {
                #pragma unroll
                for (int reg = 0; reg < 4; ++reg) {
                    uint32_t bk = 0xFFFFFFFFu, sk = 0xFFFFFFFFu;
                    #pragma unroll
                    for (int ni = 0; ni < 4; ++ni) {
                        const float d = fmaf(-2.0f, acc[mi][ni][reg], csv[ni]);
                        const uint32_t key = (sortable(d) & 0xFFFFFFC0u)
                                           | (uint32_t)(ni * 16 + (lane & 15));
                        const uint32_t nb = umin32(bk, key);
                        sk = umin32(sk, umax32(bk, key));
                        bk = nb;
                    }
                    #pragma unroll
                    for (int m = 1; m < 16; m <<= 1) {
                        const uint32_t ob = __shfl_xor((int)bk, m, 16);
                        const uint32_t os = __shfl_xor((int)sk, m, 16);
                        const uint32_t nb = umin32(bk, ob);
                        sk = umin32(umin32(sk, os), umax32(bk, ob));
                        bk = nb;
                    }
                    if ((lane & 15) == 0) {
                        const int row = r0t + wm * 128 + mi * 16 + (lane >> 4) * 4 + reg;
                        uint2 v; v.x = bk; v.y = sk;
                        *(uint2*)(winners + (size_t)row * 512 + gt * 2) = v;
                    }
                }
            }
            #pragma unroll
            for (int mi = 0; mi < 8; ++mi)
                #pragma unroll
                for (int ni = 0; ni < 4; ++ni)
                    acc[mi][ni] = (f32x4){0.f, 0.f, 0.f, 0.f};
        }
    }
#undef STEP
#undef STAGE
#undef AOFF
#undef BOFF
#undef BAR
#undef LGKM0
#undef MFMA32
}

// ---------------------------------------------------------------------------
// Per token (one wave): approx top-8 of the 512 stored u32 keys, exact fp32
// rescore, pick true argmin (np tie-break), then fused residual update:
//   r[t] -= cb[best];  r16[t] = bf16(r[t])
// key -> global col: slot j holds tile j>>1 (64-col granule), col low 6 bits.
// ---------------------------------------------------------------------------
__global__ __launch_bounds__(256)
void select_rescore(const uint32_t* __restrict__ winners,
                    const float* __restrict__ CB, const float* __restrict__ csq,
                    float* __restrict__ R, __bf16* __restrict__ R16)
{
    const int w = threadIdx.x >> 6;
    const int lane = threadIdx.x & 63;
    const int token = blockIdx.x * 4 + w;

    const uint32_t* wt = winners + (size_t)token * 512;
    uint4 q0 = *(const uint4*)(wt + lane * 8);
    uint4 q1 = *(const uint4*)(wt + lane * 8 + 4);
    uint32_t k32[8] = {q0.x, q0.y, q0.z, q0.w, q1.x, q1.y, q1.z, q1.w};

    unsigned long long v[8];
    #pragma unroll
    for (int j = 0; j < 8; ++j) {
        const int gcol = ((lane * 8 + j) >> 1) * 64 + (int)(k32[j] & 63u);
        v[j] = ((unsigned long long)k32[j] << 32) | (uint32_t)gcol;
    }

    unsigned long long cand[TOPK];
    #pragma unroll
    for (int t = 0; t < TOPK; ++t) {
        unsigned long long mm = v[0];
        #pragma unroll
        for (int j = 1; j < 8; ++j) mm = umin64(mm, v[j]);
        #pragma unroll
        for (int m = 1; m < 64; m <<= 1)
            mm = umin64(mm, __shfl_xor(mm, m, 64));
        cand[t] = mm;
        #pragma unroll
        for (int j = 0; j < 8; ++j) if (v[j] == mm) v[j] = ~0ull;
    }

    // exact rescore in fp32
    float4 r0 = *(const float4*)(R + (size_t)token * 512 + lane * 8);
    float4 r1 = *(const float4*)(R + (size_t)token * 512 + lane * 8 + 4);

    unsigned long long best = ~0ull;
    #pragma unroll
    for (int t = 0; t < TOPK; ++t) {
        const int col = (int)(cand[t] & 0xFFFFFFFFull);
        const float4 c0 = *(const float4*)(CB + (size_t)col * 512 + lane * 8);
        const float4 c1 = *(const float4*)(CB + (size_t)col * 512 + lane * 8 + 4);
        float dot = r0.x * c0.x;
        dot = fmaf(r0.y, c0.y, dot); dot = fmaf(r0.z, c0.z, dot);
        dot = fmaf(r0.w, c0.w, dot); dot = fmaf(r1.x, c1.x, dot);
        dot = fmaf(r1.y, c1.y, dot); dot = fmaf(r1.z, c1.z, dot);
        dot = fmaf(r1.w, c1.w, dot);
        #pragma unroll
        for (int m = 1; m < 64; m <<= 1) dot += __shfl_xor(dot, m, 64);
        const float d = fmaf(-2.0f, dot, csq[col]);
        best = umin64(best, pack_di(d, col));
    }

    const int bcol = (int)(best & 0xFFFFFFFFull);
    const float4 c0 = *(const float4*)(CB + (size_t)bcol * 512 + lane * 8);
    const float4 c1 = *(const float4*)(CB + (size_t)bcol * 512 + lane * 8 + 4);
    r0.x -= c0.x; r0.y -= c0.y; r0.z -= c0.z; r0.w -= c0.w;
    r1.x -= c1.x; r1.y -= c1.y; r1.z -= c1.z; r1.w -= c1.w;
    *(float4*)(R + (size_t)token * 512 + lane * 8) = r0;
    *(float4*)(R + (size_t)token * 512 + lane * 8 + 4) = r1;
    bf16x8 h;
    h[0] = (__bf16)r0.x; h[1] = (__bf16)r0.y; h[2] = (__bf16)r0.z; h[3] = (__bf16)r0.w;
    h[4] = (__bf16)r1.x; h[5] = (__bf16)r1.y; h[6] = (__bf16)r1.z; h[7] = (__bf16)r1.w;
    *(bf16x8*)(R16 + (size_t)token * 512 + lane * 8) = h;
}

// ---------------------------------------------------------------------------
// Codebook prep (fused): c_sq[k] = ||cb[k]||^2 (fp32) and cb16 = bf16(cb)
// ---------------------------------------------------------------------------
__global__ __launch_bounds__(256)
void prep_cb(const float* __restrict__ CB, float* __restrict__ c_sq,
             __bf16* __restrict__ cb16)
{
    const int wave = threadIdx.x >> 6;
    const int lane = threadIdx.x & 63;
    const int row = blockIdx.x * 4 + wave;
    const float* p = CB + (size_t)row * DD + lane * 8;
    const float4 a = *(const float4*)p;
    const float4 b = *(const float4*)(p + 4);
    bf16x8 h;
    h[0] = (__bf16)a.x; h[1] = (__bf16)a.y; h[2] = (__bf16)a.z; h[3] = (__bf16)a.w;
    h[4] = (__bf16)b.x; h[5] = (__bf16)b.y; h[6] = (__bf16)b.z; h[7] = (__bf16)b.w;
    *(bf16x8*)(cb16 + (size_t)row * DD + lane * 8) = h;
    float s = a.x*a.x + a.y*a.y + a.z*a.z + a.w*a.w
            + b.x*b.x + b.y*b.y + b.z*b.z + b.w*b.w;
    #pragma unroll
    for (int m = 1; m < 64; m <<= 1) s += __shfl_xor(s, m, 64);
    if (lane == 0) c_sq[row] = s;
}

// ---------------------------------------------------------------------------
extern "C" void kernel_launch(void* const* d_in, const int* in_sizes, int n_in,
                              void* d_out, int out_size, void* d_ws, size_t ws_size,
                              hipStream_t stream)
{
    const float* x    = (const float*)d_in[0];
    const float* encw = (const float*)d_in[1];
    const float* encb = (const float*)d_in[2];
    const float* cb   = (const float*)d_in[3];
    const float* decw = (const float*)d_in[4];
    const float* decb = (const float*)d_in[5];
    float* out = (float*)d_out;

    // ws layout: z (32MB) | r (32MB) | cb16 (16MB) | r16 (16MB) | csq  (~96.1MB)
    float* z    = (float*)d_ws;                                  // TT*DD f32
    float* r    = z + (size_t)TT * DD;                           // TT*DD f32
    __bf16* cb16 = (__bf16*)(r + (size_t)TT * DD);               // KK*512 bf16
    __bf16* r16  = cb16 + (size_t)KK * DD;                       // TT*512 bf16
    float* csq  = (float*)(r16 + (size_t)TT * DD);               // KK f32
    // winners table lives in d_out (33.5 MB) — dead before decoder writes out
    uint32_t* winners = (uint32_t*)d_out;                        // TT*512 u32

    const dim3 blk(256);

    // encoder (MFMA hi/lo): z = x @ enc_w^T + enc_b ; r = z ; r16 = bf16(z)
    gemm_mfma<0><<<dim3(DD / 128, TT / 128), blk, 0, stream>>>(
        x, nullptr, encw, encb, z, r, r16);

    // codebook: exact squared norms + bf16 copy (fused, once per call)
    prep_cb<<<dim3(KK / 4), blk, 0, stream>>>(cb, csq, cb16);

    for (int s = 0; s < 2; ++s) {
        // 512 blocks = 64 code-tiles x 8 token-groups (CHAIN=8 tiles each);
        // 64 KB LDS -> 2 blocks/CU -> all 512 resident in one round.
        dist_approx8<<<dim3((KK / 256) * (TT / 256 / CHAIN)), dim3(512), 0, stream>>>(
            r16, cb16, csq, winners);
        select_rescore<<<dim3(TT / 4), blk, 0, stream>>>(winners, cb, csq, r, r16);
    }

    // decoder (MFMA hi/lo): out = (z - r) @ dec_w^T + dec_b
    gemm_mfma<1><<<dim3(DD / 128, TT / 128), blk, 0, stream>>>(
        z, r, decw, decb, out, nullptr, nullptr);
}

// Round 5
// 1035.959 us; speedup vs baseline: 7.6277x; 7.6277x over previous
//
#include <hip/hip_runtime.h>
#include <stdint.h>

// Problem constants (B=4, N=4096, D=512, K=16384, NUM_Q=2)
constexpr int TT = 16384;   // tokens = B*N
constexpr int DD = 512;     // feature dim
constexpr int KK = 16384;   // codebook size
constexpr int TOPK = 8;     // exact-rescore candidates per token

typedef __bf16 bf16x8 __attribute__((ext_vector_type(8)));
typedef __bf16 bf16x4 __attribute__((ext_vector_type(4)));
typedef float f32x4 __attribute__((ext_vector_type(4)));

typedef const __attribute__((address_space(1))) void* gas_ptr;
typedef __attribute__((address_space(3))) void* las_ptr;

// Monotone float -> sortable u32, packed with index. u64 min == (min dist, then min idx),
// matching np.argmin first-occurrence tie-break. (used in exact rescore)
__device__ __forceinline__ unsigned long long pack_di(float d, int idx) {
    uint32_t u = __float_as_uint(d);
    u = (u & 0x80000000u) ? ~u : (u | 0x80000000u);
    return ((unsigned long long)u << 32) | (uint32_t)idx;
}

__device__ __forceinline__ unsigned long long umin64(unsigned long long a,
                                                     unsigned long long b) {
    return a < b ? a : b;
}
__device__ __forceinline__ uint32_t umin32(uint32_t a, uint32_t b) { return a < b ? a : b; }
__device__ __forceinline__ uint32_t umax32(uint32_t a, uint32_t b) { return a > b ? a : b; }

// fp32 -> sortable u32 (monotone)
__device__ __forceinline__ uint32_t sortable(float d) {
    uint32_t u = __float_as_uint(d);
    return u ^ ((uint32_t)((int32_t)u >> 31) | 0x80000000u);
}

// ---------------------------------------------------------------------------
// bf16-MFMA GEMM with fp32-grade accuracy via hi/lo split (3 products):
//   out[m][n] = sum_k Ain[m][k] * W[n][k] + bias[n]
// MODE 0: Ain = A       ; writes out0 (z), out1 (r copy), out2 (bf16 z)
// MODE 1: Ain = A - A2  ; writes out0 only
// 128x128 tile, BK=64, 4 waves 4x1 (32 rows x 128 cols each). N = 512.
// ---------------------------------------------------------------------------
template<int MODE>
__global__ __launch_bounds__(256)
void gemm_mfma(const float* __restrict__ A, const float* __restrict__ A2,
               const float* __restrict__ W, const float* __restrict__ bias,
               float* __restrict__ out0, float* __restrict__ out1,
               __bf16* __restrict__ out2)
{
    __shared__ __bf16 Ah[128 * 64], Al[128 * 64];
    __shared__ __bf16 Bh[128 * 64], Bl[128 * 64];   // 64 KB total
    const int tid = threadIdx.x;
    const int lane = tid & 63;
    const int w = tid >> 6;
    const int row0 = blockIdx.y * 128;
    const int col0 = blockIdx.x * 128;

    f32x4 acc[2][8] = {};

    // staging coords: thread t covers (row = i*16 + t>>4, fp32 cols scol..scol+3)
    const int sr = tid >> 4;            // 0..15
    const int scol = (tid & 15) * 4;    // 0..60
    const int lcol = (((scol >> 3) ^ (sr & 7)) << 3) + (scol & 7);

    int a_off[2], b_off[8];
    #pragma unroll
    for (int mi = 0; mi < 2; ++mi) {
        const int ar = w * 32 + mi * 16 + (lane & 15);
        a_off[mi] = ar * 64 + (((lane >> 4) ^ (ar & 7)) << 3);
    }
    #pragma unroll
    for (int ni = 0; ni < 8; ++ni) {
        const int br = ni * 16 + (lane & 15);
        b_off[ni] = br * 64 + (((lane >> 4) ^ (br & 7)) << 3);
    }

    for (int kb = 0; kb < 512; kb += 64) {
        __syncthreads();
        #pragma unroll
        for (int i = 0; i < 8; ++i) {
            const int r = i * 16 + sr;
            float4 v = *(const float4*)(A + (size_t)(row0 + r) * 512 + kb + scol);
            if (MODE == 1) {
                const float4 u = *(const float4*)(A2 + (size_t)(row0 + r) * 512 + kb + scol);
                v.x -= u.x; v.y -= u.y; v.z -= u.z; v.w -= u.w;
            }
            bf16x4 hv, lv;
            hv[0] = (__bf16)v.x; hv[1] = (__bf16)v.y; hv[2] = (__bf16)v.z; hv[3] = (__bf16)v.w;
            lv[0] = (__bf16)(v.x - (float)hv[0]); lv[1] = (__bf16)(v.y - (float)hv[1]);
            lv[2] = (__bf16)(v.z - (float)hv[2]); lv[3] = (__bf16)(v.w - (float)hv[3]);
            *(bf16x4*)(Ah + r * 64 + lcol) = hv;
            *(bf16x4*)(Al + r * 64 + lcol) = lv;

            const float4 x = *(const float4*)(W + (size_t)(col0 + r) * 512 + kb + scol);
            bf16x4 hw, lw;
            hw[0] = (__bf16)x.x; hw[1] = (__bf16)x.y; hw[2] = (__bf16)x.z; hw[3] = (__bf16)x.w;
            lw[0] = (__bf16)(x.x - (float)hw[0]); lw[1] = (__bf16)(x.y - (float)hw[1]);
            lw[2] = (__bf16)(x.z - (float)hw[2]); lw[3] = (__bf16)(x.w - (float)hw[3]);
            *(bf16x4*)(Bh + r * 64 + lcol) = hw;
            *(bf16x4*)(Bl + r * 64 + lcol) = lw;
        }
        __syncthreads();
        #pragma unroll
        for (int s = 0; s < 2; ++s) {
            const int sx = s * 32;
            bf16x8 ah[2], al[2];
            #pragma unroll
            for (int mi = 0; mi < 2; ++mi) {
                ah[mi] = *(const bf16x8*)(Ah + (a_off[mi] ^ sx));
                al[mi] = *(const bf16x8*)(Al + (a_off[mi] ^ sx));
            }
            #pragma unroll
            for (int ni = 0; ni < 8; ++ni) {
                const bf16x8 bh = *(const bf16x8*)(Bh + (b_off[ni] ^ sx));
                const bf16x8 bl = *(const bf16x8*)(Bl + (b_off[ni] ^ sx));
                #pragma unroll
                for (int mi = 0; mi < 2; ++mi) {
                    acc[mi][ni] = __builtin_amdgcn_mfma_f32_16x16x32_bf16(ah[mi], bh, acc[mi][ni], 0, 0, 0);
                    acc[mi][ni] = __builtin_amdgcn_mfma_f32_16x16x32_bf16(ah[mi], bl, acc[mi][ni], 0, 0, 0);
                    acc[mi][ni] = __builtin_amdgcn_mfma_f32_16x16x32_bf16(al[mi], bh, acc[mi][ni], 0, 0, 0);
                }
            }
        }
    }

    #pragma unroll
    for (int mi = 0; mi < 2; ++mi) {
        #pragma unroll
        for (int reg = 0; reg < 4; ++reg) {
            const int row = row0 + w * 32 + mi * 16 + (lane >> 4) * 4 + reg;
            #pragma unroll
            for (int ni = 0; ni < 8; ++ni) {
                const int col = col0 + ni * 16 + (lane & 15);
                const float o = acc[mi][ni][reg] + bias[col];
                out0[(size_t)row * 512 + col] = o;
                if (MODE == 0) {
                    out1[(size_t)row * 512 + col] = o;
                    out2[(size_t)row * 512 + col] = (__bf16)o;
                }
            }
        }
    }
}

// ---------------------------------------------------------------------------
// Approx distance pass, 128x128 tile, 4 waves, BK=32 dbuf, 32 KB LDS:
//   d[t][c] ~= csq[c] - 2 * (r16[t] . cb16[c])
// R4 post-mortem: __launch_bounds__(512,4) forced a 128-reg cap on a kernel
// needing ~256 -> acc spilled to scratch (VGPR_Count 64, WRITE_SIZE 11.3 GB).
// The occupancy hypothesis was never tested. This version makes higher
// occupancy FEASIBLE by register arithmetic: wave tile 64x64 (acc[4][4] = 64
// regs), 4-wave blocks, per-wave total ~130 regs; __launch_bounds__(256,3)
// caps at ~170 (no spill possible). LDS = 32 KB -> 3 blocks/CU = 12 waves/CU,
// three INDEPENDENT barrier/waitcnt domains per CU (m114: independent waves
// overlap fully) to fill each block's sync bubbles -- the stall class that
// pinned R1-R3 at ~33% MfmaUtil with one resident block.
// Per K-step (32 k): read 8 frags | lgkm0 | BAR1 | stage step s+2 (same
// buffer, now safe) | 16 MFMA | vmcnt(4) | BAR2. Ledger: at vmcnt(4),
// outstanding = stage(s+1)[4] + stage(s+2)[4]; retiring to 4 completes
// exactly stage(s+1) = next step's buffer. Tail steps drain to 0.
// Swizzle (BK=32): physical 16B chunk = logical ^ ((row>>1)&3); rows +64
// preserve the term (64>>1 = 32 === 0 mod 4) -> one source pointer per
// thread. Measured 0 bank conflicts in R3/R4 with this scheme.
// CHAIN=8 token tiles per block; grid 2048 = 128 code-tiles x 16 groups.
// XCD stripe: xcd owns 16 code tiles -> resident B-panels 2 MB/XCD (L2).
// Epilogue per finished token tile: top-2 over wave's 64 cols, u32 keys,
// identical layout/tie-break to the verified R0 64x64-wave version.
// ---------------------------------------------------------------------------
constexpr int CHAIN = 8;                      // token tiles chained per block
constexpr int NSTEP = 16 * CHAIN;             // K-steps of 32 per block
constexpr size_t TILE_A = 128 * 512;          // elems per 128-row token tile

__global__ __launch_bounds__(256, 3)
void dist_approx4(const __bf16* __restrict__ Rh,   // [TT][512]
                  const __bf16* __restrict__ Ch,   // [KK][512]
                  const float* __restrict__ csq,
                  uint32_t* __restrict__ winners)
{
    __shared__ __bf16 As[2][128 * 32];   // 8 KB each
    __shared__ __bf16 Bs[2][128 * 32];   // -> 32 KB total

    const int tid  = threadIdx.x;
    const int lane = tid & 63;
    const int w    = tid >> 6;        // 0..3
    const int wm   = w >> 1;          // 0..1 : token half (64 rows)
    const int wn   = w & 1;           // 0..1 : code half (64 cols)

    // XCD column-stripe: xcd = b&7 owns code tiles [16*xcd, 16*xcd+16)
    const int b    = blockIdx.x;              // 0..2047
    const int xcd  = b & 7;
    const int i    = b >> 3;                  // 0..255
    const int ct   = xcd * 16 + (i & 15);     // code tile 0..127 (128 cols)
    const int tg   = i >> 4;                  // token group 0..15
    const int col0 = ct << 7;                 // code tile base
    const int rowb = tg << 10;                // 1024-token group base

    f32x4 acc[4][4] = {};   // [mi][ni] -- 64 regs

    // staging coords: LDS stays linear for global_load_lds; swizzle applied on
    // the GLOBAL side. One 4 KB load = 64 rows x 64 B: thread covers row
    // tid>>2 (0..63; +64 in 2nd load), physical chunk tid&3 holding logical
    // chunk (tid&3)^((row>>1)&3)  (involution).
    const int s_r = tid >> 2;                          // 0..63
    const int s_c = (tid & 3) ^ ((s_r >> 1) & 3);      // logical 16B chunk
    const __bf16* aS = Rh + (size_t)(rowb + s_r) * 512 + s_c * 8;
    const __bf16* bS = Ch + (size_t)(col0 + s_r) * 512 + s_c * 8;
    __bf16* const lA0 = &As[0][0]; __bf16* const lA1 = &As[1][0];
    __bf16* const lB0 = &Bs[0][0]; __bf16* const lB1 = &Bs[1][0];

    // A-source offset for K-step q (q = 0..NSTEP-1): tile (q>>4), k-block (q&15)
#define AOFF(q) ((size_t)((q) >> 4) * TILE_A + (size_t)((q) & 15) * 32)
#define BOFF(q) ((size_t)((q) & 15) * 32)

    // one K-step panel (128 rows x 32 cols) = 2 x (256 thr x 16 B) = 8 KB
    // wave-uniform LDS bases: load0 rows 0..63 (wave w -> +w*512 elems),
    // load1 rows 64..127.
#define STAGE(SRC, UOFF, DST)                                                      \
    {                                                                              \
        __builtin_amdgcn_global_load_lds((gas_ptr)((SRC) + (UOFF)),                \
                                         (las_ptr)((DST) + w * 512), 16, 0, 0);    \
        __builtin_amdgcn_global_load_lds((gas_ptr)((SRC) + (UOFF) + 64 * 512),     \
                                         (las_ptr)((DST) + 64 * 32 + w * 512), 16, 0, 0); \
    }

    // fragment LDS offsets (elems), swizzle-compensated
    int aoff[4], boff[4];
    #pragma unroll
    for (int mi = 0; mi < 4; ++mi) {
        const int r = wm * 64 + mi * 16 + (lane & 15);
        aoff[mi] = r * 32 + ((((lane >> 4) ^ ((r >> 1) & 3))) << 3);
    }
    #pragma unroll
    for (int ni = 0; ni < 4; ++ni) {
        const int r = wn * 64 + ni * 16 + (lane & 15);
        boff[ni] = r * 32 + ((((lane >> 4) ^ ((r >> 1) & 3))) << 3);
    }

#define BAR __builtin_amdgcn_s_barrier()
// full lgkm drain + scheduling fence: this wave's ds_reads have COMPLETED
// (data in VGPRs) before anything below (barrier / MFMA) runs.
#define LGKM0 { asm volatile("s_waitcnt lgkmcnt(0)" ::: "memory"); \
                __builtin_amdgcn_sched_barrier(0); }
#define MFMA16(AF, BV)                                                         \
    {                                                                          \
        __builtin_amdgcn_s_setprio(1);                                         \
        _Pragma("unroll")                                                      \
        for (int mi = 0; mi < 4; ++mi) {                                       \
            _Pragma("unroll")                                                  \
            for (int ni = 0; ni < 4; ++ni)                                     \
                acc[mi][ni] = __builtin_amdgcn_mfma_f32_16x16x32_bf16(         \
                    (AF)[mi], (BV)[ni], acc[mi][ni], 0, 0, 0);                 \
        }                                                                      \
        __builtin_amdgcn_s_setprio(0);                                         \
    }

// one K-step: read frags from (LA,LB); drain; BAR1 licenses same-buffer
// overwrite; stage step S+2; 16 MFMA; counted vmcnt retires stage(S+1);
// BAR2 licenses next step's buffer reads.
#define STEP(LA, LB, S)                                                        \
    {                                                                          \
        _Pragma("unroll")                                                      \
        for (int mi = 0; mi < 4; ++mi) af[mi] = *(const bf16x8*)((LA) + aoff[mi]); \
        _Pragma("unroll")                                                      \
        for (int ni = 0; ni < 4; ++ni) bfr[ni] = *(const bf16x8*)((LB) + boff[ni]); \
        LGKM0;                                                                 \
        BAR;                                                                   \
        const bool more_ = (S) + 2 < NSTEP;                                    \
        if (more_) {                                                           \
            STAGE(aS, AOFF((S) + 2), (LA));                                    \
            STAGE(bS, BOFF((S) + 2), (LB));                                    \
        }                                                                      \
        MFMA16(af, bfr);                                                       \
        if (more_) { asm volatile("s_waitcnt vmcnt(4)" ::: "memory"); }        \
        else       { asm volatile("s_waitcnt vmcnt(0)" ::: "memory"); }        \
        BAR;                                                                   \
    }

    // ---- csq hoist (col0 is block-invariant)
    float csv[4];
    #pragma unroll
    for (int ni = 0; ni < 4; ++ni)
        csv[ni] = csq[col0 + wn * 64 + ni * 16 + (lane & 15)];
    const int gt = (col0 >> 6) + wn;   // winners 64-col granule index (0..255)

    // ---- prologue: step0 A+B -> buf0 (4 loads), step1 A+B -> buf1 (4 loads)
    STAGE(aS, AOFF(0), lA0);
    STAGE(bS, BOFF(0), lB0);
    STAGE(aS, AOFF(1), lA1);
    STAGE(bS, BOFF(1), lB1);
    asm volatile("s_waitcnt vmcnt(4)" ::: "memory");
    BAR;

    bf16x8 af[4], bfr[4];

    for (int it = 0; it < 8 * CHAIN; ++it) {
        STEP(lA0, lB0, 2 * it);          // even step: buffer 0
        STEP(lA1, lB1, 2 * it + 1);      // odd step:  buffer 1

        // ---- per-tile epilogue: token tile finished every 8 iterations.
        // Top-2 over this wave's 64 cols, u32 keys; C/D layout (16x16x32):
        // col = lane&15, row = (lane>>4)*4 + reg.  Then re-zero acc.
        // Winner stores enter the vmcnt queue; the next step's vmcnt(4) is
        // then conservative (waits longer), never unsafe.
        if ((it & 7) == 7) {
            const int r0t = rowb + (it >> 3) * 128;
            #pragma unroll
            for (int mi = 0; mi < 4; ++mi) {
                #pragma unroll
                for (int reg = 0; reg < 4; ++reg) {
                    uint32_t bk = 0xFFFFFFFFu, sk = 0xFFFFFFFFu;
                    #pragma unroll
                    for (int ni = 0; ni < 4; ++ni) {
                        const float d = fmaf(-2.0f, acc[mi][ni][reg], csv[ni]);
                        const uint32_t key = (sortable(d) & 0xFFFFFFC0u)
                                           | (uint32_t)(ni * 16 + (lane & 15));
                        const uint32_t nb = umin32(bk, key);
                        sk = umin32(sk, umax32(bk, key));
                        bk = nb;
                    }
                    #pragma unroll
                    for (int m = 1; m < 16; m <<= 1) {
                        const uint32_t ob = __shfl_xor((int)bk, m, 16);
                        const uint32_t os = __shfl_xor((int)sk, m, 16);
                        const uint32_t nb = umin32(bk, ob);
                        sk = umin32(umin32(sk, os), umax32(bk, ob));
                        bk = nb;
                    }
                    if ((lane & 15) == 0) {
                        const int row = r0t + wm * 64 + mi * 16 + (lane >> 4) * 4 + reg;
                        uint2 v; v.x = bk; v.y = sk;
                        *(uint2*)(winners + (size_t)row * 512 + gt * 2) = v;
                    }
                }
            }
            #pragma unroll
            for (int mi = 0; mi < 4; ++mi)
                #pragma unroll
                for (int ni = 0; ni < 4; ++ni)
                    acc[mi][ni] = (f32x4){0.f, 0.f, 0.f, 0.f};
        }
    }
#undef STEP
#undef STAGE
#undef AOFF
#undef BOFF
#undef BAR
#undef LGKM0
#undef MFMA16
}

// ---------------------------------------------------------------------------
// Per token (one wave): approx top-8 of the 512 stored u32 keys, exact fp32
// rescore, pick true argmin (np tie-break), then fused residual update:
//   r[t] -= cb[best];  r16[t] = bf16(r[t])
// key -> global col: slot j holds tile j>>1 (64-col granule), col low 6 bits.
// ---------------------------------------------------------------------------
__global__ __launch_bounds__(256)
void select_rescore(const uint32_t* __restrict__ winners,
                    const float* __restrict__ CB, const float* __restrict__ csq,
                    float* __restrict__ R, __bf16* __restrict__ R16)
{
    const int w = threadIdx.x >> 6;
    const int lane = threadIdx.x & 63;
    const int token = blockIdx.x * 4 + w;

    const uint32_t* wt = winners + (size_t)token * 512;
    uint4 q0 = *(const uint4*)(wt + lane * 8);
    uint4 q1 = *(const uint4*)(wt + lane * 8 + 4);
    uint32_t k32[8] = {q0.x, q0.y, q0.z, q0.w, q1.x, q1.y, q1.z, q1.w};

    unsigned long long v[8];
    #pragma unroll
    for (int j = 0; j < 8; ++j) {
        const int gcol = ((lane * 8 + j) >> 1) * 64 + (int)(k32[j] & 63u);
        v[j] = ((unsigned long long)k32[j] << 32) | (uint32_t)gcol;
    }

    unsigned long long cand[TOPK];
    #pragma unroll
    for (int t = 0; t < TOPK; ++t) {
        unsigned long long mm = v[0];
        #pragma unroll
        for (int j = 1; j < 8; ++j) mm = umin64(mm, v[j]);
        #pragma unroll
        for (int m = 1; m < 64; m <<= 1)
            mm = umin64(mm, __shfl_xor(mm, m, 64));
        cand[t] = mm;
        #pragma unroll
        for (int j = 0; j < 8; ++j) if (v[j] == mm) v[j] = ~0ull;
    }

    // exact rescore in fp32
    float4 r0 = *(const float4*)(R + (size_t)token * 512 + lane * 8);
    float4 r1 = *(const float4*)(R + (size_t)token * 512 + lane * 8 + 4);

    unsigned long long best = ~0ull;
    #pragma unroll
    for (int t = 0; t < TOPK; ++t) {
        const int col = (int)(cand[t] & 0xFFFFFFFFull);
        const float4 c0 = *(const float4*)(CB + (size_t)col * 512 + lane * 8);
        const float4 c1 = *(const float4*)(CB + (size_t)col * 512 + lane * 8 + 4);
        float dot = r0.x * c0.x;
        dot = fmaf(r0.y, c0.y, dot); dot = fmaf(r0.z, c0.z, dot);
        dot = fmaf(r0.w, c0.w, dot); dot = fmaf(r1.x, c1.x, dot);
        dot = fmaf(r1.y, c1.y, dot); dot = fmaf(r1.z, c1.z, dot);
        dot = fmaf(r1.w, c1.w, dot);
        #pragma unroll
        for (int m = 1; m < 64; m <<= 1) dot += __shfl_xor(dot, m, 64);
        const float d = fmaf(-2.0f, dot, csq[col]);
        best = umin64(best, pack_di(d, col));
    }

    const int bcol = (int)(best & 0xFFFFFFFFull);
    const float4 c0 = *(const float4*)(CB + (size_t)bcol * 512 + lane * 8);
    const float4 c1 = *(const float4*)(CB + (size_t)bcol * 512 + lane * 8 + 4);
    r0.x -= c0.x; r0.y -= c0.y; r0.z -= c0.z; r0.w -= c0.w;
    r1.x -= c1.x; r1.y -= c1.y; r1.z -= c1.z; r1.w -= c1.w;
    *(float4*)(R + (size_t)token * 512 + lane * 8) = r0;
    *(float4*)(R + (size_t)token * 512 + lane * 8 + 4) = r1;
    bf16x8 h;
    h[0] = (__bf16)r0.x; h[1] = (__bf16)r0.y; h[2] = (__bf16)r0.z; h[3] = (__bf16)r0.w;
    h[4] = (__bf16)r1.x; h[5] = (__bf16)r1.y; h[6] = (__bf16)r1.z; h[7] = (__bf16)r1.w;
    *(bf16x8*)(R16 + (size_t)token * 512 + lane * 8) = h;
}

// ---------------------------------------------------------------------------
// Codebook prep (fused): c_sq[k] = ||cb[k]||^2 (fp32) and cb16 = bf16(cb)
// ---------------------------------------------------------------------------
__global__ __launch_bounds__(256)
void prep_cb(const float* __restrict__ CB, float* __restrict__ c_sq,
             __bf16* __restrict__ cb16)
{
    const int wave = threadIdx.x >> 6;
    const int lane = threadIdx.x & 63;
    const int row = blockIdx.x * 4 + wave;
    const float* p = CB + (size_t)row * DD + lane * 8;
    const float4 a = *(const float4*)p;
    const float4 b = *(const float4*)(p + 4);
    bf16x8 h;
    h[0] = (__bf16)a.x; h[1] = (__bf16)a.y; h[2] = (__bf16)a.z; h[3] = (__bf16)a.w;
    h[4] = (__bf16)b.x; h[5] = (__bf16)b.y; h[6] = (__bf16)b.z; h[7] = (__bf16)b.w;
    *(bf16x8*)(cb16 + (size_t)row * DD + lane * 8) = h;
    float s = a.x*a.x + a.y*a.y + a.z*a.z + a.w*a.w
            + b.x*b.x + b.y*b.y + b.z*b.z + b.w*b.w;
    #pragma unroll
    for (int m = 1; m < 64; m <<= 1) s += __shfl_xor(s, m, 64);
    if (lane == 0) c_sq[row] = s;
}

// ---------------------------------------------------------------------------
extern "C" void kernel_launch(void* const* d_in, const int* in_sizes, int n_in,
                              void* d_out, int out_size, void* d_ws, size_t ws_size,
                              hipStream_t stream)
{
    const float* x    = (const float*)d_in[0];
    const float* encw = (const float*)d_in[1];
    const float* encb = (const float*)d_in[2];
    const float* cb   = (const float*)d_in[3];
    const float* decw = (const float*)d_in[4];
    const float* decb = (const float*)d_in[5];
    float* out = (float*)d_out;

    // ws layout: z (32MB) | r (32MB) | cb16 (16MB) | r16 (16MB) | csq  (~96.1MB)
    float* z    = (float*)d_ws;                                  // TT*DD f32
    float* r    = z + (size_t)TT * DD;                           // TT*DD f32
    __bf16* cb16 = (__bf16*)(r + (size_t)TT * DD);               // KK*512 bf16
    __bf16* r16  = cb16 + (size_t)KK * DD;                       // TT*512 bf16
    float* csq  = (float*)(r16 + (size_t)TT * DD);               // KK f32
    // winners table lives in d_out (33.5 MB) — dead before decoder writes out
    uint32_t* winners = (uint32_t*)d_out;                        // TT*512 u32

    const dim3 blk(256);

    // encoder (MFMA hi/lo): z = x @ enc_w^T + enc_b ; r = z ; r16 = bf16(z)
    gemm_mfma<0><<<dim3(DD / 128, TT / 128), blk, 0, stream>>>(
        x, nullptr, encw, encb, z, r, r16);

    // codebook: exact squared norms + bf16 copy (fused, once per call)
    prep_cb<<<dim3(KK / 4), blk, 0, stream>>>(cb, csq, cb16);

    for (int s = 0; s < 2; ++s) {
        // 2048 blocks = 128 code-tiles x 16 token-groups (CHAIN=8 tiles each);
        // 32 KB LDS + <=170 regs -> 3 blocks/CU (12 waves/CU), independent.
        dist_approx4<<<dim3((KK / 128) * (TT / 128 / CHAIN)), dim3(256), 0, stream>>>(
            r16, cb16, csq, winners);
        select_rescore<<<dim3(TT / 4), blk, 0, stream>>>(winners, cb, csq, r, r16);
    }

    // decoder (MFMA hi/lo): out = (z - r) @ dec_w^T + dec_b
    gemm_mfma<1><<<dim3(DD / 128, TT / 128), blk, 0, stream>>>(
        z, r, decw, decb, out, nullptr, nullptr);
}